// Round 1
// baseline (463.780 us; speedup 1.0000x reference)
//
#include <hip/hip_runtime.h>
#include <hip/hip_bf16.h>

// Problem constants
#define VN 10000
#define HID 128
#define GRID_MAIN 512
// W1 rows (161 x 128): [0,64) Wh, [64,128) Wm, 128 Wt, [129,161) Wp

using bf16x8 = __attribute__((ext_vector_type(8))) __bf16;
using f32x4  = __attribute__((ext_vector_type(4))) float;

// ---------------------------------------------------------------------------
// prep_kernel (unchanged, verified):
//   blocks [0,625): base[v][h] = b1[h] + h_t[v]@Wh + theta[v]@Wp   (fp32)
//   blocks [625,657): wmt[n*64+d] = bf16(Wm[d][n])  (transposed, n-major)
// ---------------------------------------------------------------------------
__global__ __launch_bounds__(256) void prep_kernel(
    const float* __restrict__ h_t, const float* __restrict__ theta,
    const float* __restrict__ W1, const float* __restrict__ b1,
    float* __restrict__ base, __bf16* __restrict__ wmt)
{
  const int blk = blockIdx.x;
  const int tid = threadIdx.x;
  if (blk < 625) {
    __shared__ __align__(16) float in[16][96];   // 16 nodes x (64 h_t | 32 theta)
    const int v0 = blk * 16;
    {
      const float4* src = (const float4*)(h_t + (size_t)v0 * 64);
      float4 f = src[tid];
      int vl = tid >> 4, c = (tid & 15) * 4;
      *(float4*)&in[vl][c] = f;
    }
    if (tid < 128) {
      const float4* src = (const float4*)(theta + (size_t)v0 * 32);
      float4 f = src[tid];
      int vl = tid >> 3, c = 64 + (tid & 7) * 4;
      *(float4*)&in[vl][c] = f;
    }
    __syncthreads();
    const int h = tid & 127;
    const int half = tid >> 7;      // wave-uniform
    float acc[8];
    const float bb = b1[h];
    #pragma unroll
    for (int k = 0; k < 8; k++) acc[k] = bb;
    // Wh rows 0..64 : chunks of 4 d, float4 LDS broadcast reads
    #pragma unroll 4
    for (int dc = 0; dc < 16; dc++) {
      const int d = 4 * dc;
      float w0 = W1[(d + 0) * 128 + h];
      float w1 = W1[(d + 1) * 128 + h];
      float w2 = W1[(d + 2) * 128 + h];
      float w3 = W1[(d + 3) * 128 + h];
      #pragma unroll
      for (int k = 0; k < 8; k++) {
        float4 iv = *(const float4*)&in[2 * k + half][d];
        acc[k] += iv.x * w0 + iv.y * w1 + iv.z * w2 + iv.w * w3;
      }
    }
    // Wp rows 129..161 : theta part (cols 64..96 of in)
    #pragma unroll 4
    for (int dc = 0; dc < 8; dc++) {
      const int d = 4 * dc;
      float w0 = W1[(129 + d + 0) * 128 + h];
      float w1 = W1[(129 + d + 1) * 128 + h];
      float w2 = W1[(129 + d + 2) * 128 + h];
      float w3 = W1[(129 + d + 3) * 128 + h];
      #pragma unroll
      for (int k = 0; k < 8; k++) {
        float4 iv = *(const float4*)&in[2 * k + half][64 + d];
        acc[k] += iv.x * w0 + iv.y * w1 + iv.z * w2 + iv.w * w3;
      }
    }
    #pragma unroll
    for (int k = 0; k < 8; k++)
      base[(size_t)(v0 + 2 * k + half) * 128 + h] = acc[k];
  } else {
    int j = (blk - 625) * 256 + tid;   // 32 blocks * 256 = 8192 exact
    int n = j >> 6, d = j & 63;
    wmt[j] = (__bf16)W1[(64 + d) * 128 + n];     // Wm^T[n][d]
  }
}

// ---------------------------------------------------------------------------
// main_kernel: register-only persistent kernel.
//   grid = 512 blocks x 256 thr (4 waves). Block strides nodes v, v+512, ...
//   Per wave: rows [32w, 32w+32) of the 128x64 @ 64x128 bf16 MFMA.
//   B fragments (wmt, 16 KB) hoisted to 64 VGPRs ONCE per block.
//   A fragments loaded straight from global (lane reads its 32 contiguous
//   bytes: 2 x dwordx4), cvt f32->bf16 in-reg. Double-buffered node pipeline
//   (prefetch v+512 while computing v). NO LDS, NO barriers.
// ---------------------------------------------------------------------------
__global__ __launch_bounds__(256, 2) void main_kernel(
    const float* __restrict__ messages, const float* __restrict__ tau,
    const float* __restrict__ W1, const float* __restrict__ W2,
    const float* __restrict__ b2, const float* __restrict__ base,
    const __bf16* __restrict__ wmt, float* __restrict__ out)
{
  const int tid  = threadIdx.x;
  const int w    = tid >> 6;        // wave id: rows [32w, 32w+32)
  const int lane = tid & 63;
  const int quad = lane >> 4;
  const int l16  = lane & 15;
  const int rowbase = 32 * w;

  // ---- per-block loop-invariant state ----
  // B frag: lane holds Wm^T[n = nt*16+l16][k = ks*32+quad*8 .. +8]
  bf16x8 Bf[2][8];
  #pragma unroll
  for (int ks = 0; ks < 2; ks++)
    #pragma unroll
    for (int nt = 0; nt < 8; nt++)
      Bf[ks][nt] = *(const bf16x8*)(wmt + (nt * 16 + l16) * 64 + ks * 32 + quad * 8);

  float w2v[8], wtv[8];
  #pragma unroll
  for (int nt = 0; nt < 8; nt++) {
    const int n = nt * 16 + l16;
    w2v[nt] = W2[n];
    wtv[nt] = W1[128 * 128 + n];    // Wt row
  }
  const float tv0 = tau[2 * w];
  const float tv1 = tau[2 * w + 1];
  const float b2v = b2[0];

  // ---- prefetch: node v's A rows (raw f32) + base row, into named regs ----
  auto PREF = [&](int v, f32x4 (&A)[2][2][2], float (&bb)[8]) {
    const float* msg = messages + (size_t)v * 8192;
    #pragma unroll
    for (int mt = 0; mt < 2; mt++)
      #pragma unroll
      for (int ks = 0; ks < 2; ks++) {
        const float* p = msg + (rowbase + mt * 16 + l16) * 64 + ks * 32 + quad * 8;
        A[mt][ks][0] = *(const f32x4*)p;
        A[mt][ks][1] = *(const f32x4*)(p + 4);
      }
    #pragma unroll
    for (int nt = 0; nt < 8; nt++)
      bb[nt] = base[(size_t)v * 128 + nt * 16 + l16];
  };

  // ---- compute one node from prefetched registers ----
  auto COMP = [&](int v, const f32x4 (&A)[2][2][2], const float (&bb)[8]) {
    // cvt f32 -> bf16 fragments (4x bf16x8, 16 VGPR)
    bf16x8 af[2][2];
    #pragma unroll
    for (int mt = 0; mt < 2; mt++)
      #pragma unroll
      for (int ks = 0; ks < 2; ks++)
        #pragma unroll
        for (int j = 0; j < 4; j++) {
          af[mt][ks][j]     = (__bf16)A[mt][ks][0][j];
          af[mt][ks][4 + j] = (__bf16)A[mt][ks][1][j];
        }
    // per-nt accumulate + immediate epilogue fold (acc stays 8 VGPR)
    float ps0[4] = {0.f, 0.f, 0.f, 0.f};
    float ps1[4] = {0.f, 0.f, 0.f, 0.f};
    #pragma unroll
    for (int nt = 0; nt < 8; nt++) {
      f32x4 acc0 = (f32x4){0.f, 0.f, 0.f, 0.f};
      f32x4 acc1 = (f32x4){0.f, 0.f, 0.f, 0.f};
      acc0 = __builtin_amdgcn_mfma_f32_16x16x32_bf16(af[0][0], Bf[0][nt], acc0, 0, 0, 0);
      acc0 = __builtin_amdgcn_mfma_f32_16x16x32_bf16(af[0][1], Bf[1][nt], acc0, 0, 0, 0);
      acc1 = __builtin_amdgcn_mfma_f32_16x16x32_bf16(af[1][0], Bf[0][nt], acc1, 0, 0, 0);
      acc1 = __builtin_amdgcn_mfma_f32_16x16x32_bf16(af[1][1], Bf[1][nt], acc1, 0, 0, 0);
      const float add0 = bb[nt] + tv0 * wtv[nt];
      const float add1 = bb[nt] + tv1 * wtv[nt];
      #pragma unroll
      for (int r = 0; r < 4; r++) {
        ps0[r] += fmaxf(acc0[r] + add0, 0.f) * w2v[nt];
        ps1[r] += fmaxf(acc1[r] + add1, 0.f) * w2v[nt];
      }
    }
    // reduce over the 16 lanes sharing a quad (columns n) and store directly
    #pragma unroll
    for (int off = 1; off < 16; off <<= 1)
      #pragma unroll
      for (int r = 0; r < 4; r++) {
        ps0[r] += __shfl_xor(ps0[r], off, 64);
        ps1[r] += __shfl_xor(ps1[r], off, 64);
      }
    if (l16 == 0) {
      f32x4 o0, o1;
      #pragma unroll
      for (int r = 0; r < 4; r++) { o0[r] = ps0[r] + b2v; o1[r] = ps1[r] + b2v; }
      *(f32x4*)&out[(size_t)v * 128 + rowbase + quad * 4]      = o0;
      *(f32x4*)&out[(size_t)v * 128 + rowbase + 16 + quad * 4] = o1;
    }
  };

  // ---- double-buffered node pipeline ----
  f32x4 A0[2][2][2], A1[2][2][2];
  float bb0[8], bb1[8];
  int v = blockIdx.x;
  PREF(v, A0, bb0);
  while (true) {
    const int v1 = v + GRID_MAIN;
    if (v1 < VN) PREF(v1, A1, bb1);
    COMP(v, A0, bb0);
    if (v1 >= VN) break;
    const int v2 = v1 + GRID_MAIN;
    if (v2 < VN) PREF(v2, A0, bb0);
    COMP(v1, A1, bb1);
    if (v2 >= VN) break;
    v = v2;
  }
}

// ---------------------------------------------------------------------------
extern "C" void kernel_launch(void* const* d_in, const int* in_sizes, int n_in,
                              void* d_out, int out_size, void* d_ws, size_t ws_size,
                              hipStream_t stream) {
  const float* h_t      = (const float*)d_in[0];
  const float* messages = (const float*)d_in[1];
  const float* tau      = (const float*)d_in[2];
  const float* theta    = (const float*)d_in[3];
  const float* W1       = (const float*)d_in[4];
  const float* b1       = (const float*)d_in[5];
  const float* W2       = (const float*)d_in[6];
  const float* b2       = (const float*)d_in[7];
  float* out = (float*)d_out;

  // ws layout: [0, VN*128) f32 base | 8192 bf16 Wm^T
  float* base = (float*)d_ws;
  __bf16* wmt = (__bf16*)((char*)d_ws + (size_t)VN * HID * sizeof(float));

  prep_kernel<<<625 + 32, 256, 0, stream>>>(h_t, theta, W1, b1, base, wmt);
  main_kernel<<<GRID_MAIN, 256, 0, stream>>>(messages, tau, W1, W2, b2, base, wmt, out);
}